// Round 2
// baseline (236.127 us; speedup 1.0000x reference)
//
#include <hip/hip_runtime.h>
#include <hip/hip_cooperative_groups.h>
#include <stdint.h>

namespace cg = cooperative_groups;

// Problem constants
#define NB   16      // batch
#define NC   128
#define NT   8
#define NBR  16
#define NS   8
#define NSY  64
#define NIN  16384   // = NC*NT*NBR = INPUT_SIZE

#define GRID 512     // 2 blocks/CU co-resident (LDS allows 5, waves allow 8)

// ---------------------------------------------------------------------------
// One wave computes one branch's 16-batch output mask.
// lane = synapse (SY == 64 == wave width). Per segment:
//   coalesced 256B idx load -> LDS gather of 16-bit batch mask ->
//   16 ballots give all 16 per-batch segment sums (popcount over 64 lanes).
// ---------------------------------------------------------------------------
__device__ __forceinline__ uint32_t branch_mask(const uint16_t* lds,
                                                const int* __restrict__ ip /* +lane */) {
    int bs[NB];
#pragma unroll
    for (int b = 0; b < NB; ++b) bs[b] = 0;
#pragma unroll
    for (int s = 0; s < NS; ++s) {
        const int iv = ip[s * NSY];
        uint32_t m = (uint32_t)lds[iv & (NIN - 1)];
        m &= ~(uint32_t)(iv >> 31);          // zero when iv == -1
#pragma unroll
        for (int b = 0; b < NB; ++b) {
            const unsigned long long bal = __ballot(m & (1u << b));
            bs[b] += (__popcll(bal) >= 16) ? 1 : 0;   // SEG_TH
        }
    }
    uint32_t om = 0;
#pragma unroll
    for (int b = 0; b < NB; ++b)
        om |= (bs[b] >= 4) ? (1u << b) : 0u;          // BR_TH
    return om;
}

// ---------------------------------------------------------------------------
// Fused: pack -> gridsync -> layer1 -> gridsync -> layer2. GRID x 256.
// ---------------------------------------------------------------------------
__global__ __launch_bounds__(256, 4) void k_fused(const float* __restrict__ x,
                                                  const int* __restrict__ idx1,
                                                  const int* __restrict__ idx2,
                                                  uint16_t* __restrict__ xpack,
                                                  uint16_t* __restrict__ act1pack,
                                                  int* __restrict__ out) {
    cg::grid_group grid = cg::this_grid();
    __shared__ __align__(16) uint16_t lds[NIN];   // 32 KB
    const int tid  = threadIdx.x;
    const int lane = tid & 63;
    const int wave = tid >> 6;
    const int bk   = blockIdx.x;                  // 0..GRID-1

    // ---- Phase 0: pack x into 16-bit batch masks. 32 positions per block. ----
    if (wave < 2) {
        const int pos = bk * 32 + wave * 16 + (lane & 15);
        const int bg  = lane >> 4;                // 4 lanes-groups x 4 batches
        uint32_t m = 0;
#pragma unroll
        for (int j = 0; j < 4; ++j) {
            const int b = bg * 4 + j;
            m |= (x[b * NIN + pos] != 0.0f) ? (1u << b) : 0u;
        }
        m |= __shfl_xor(m, 16);
        m |= __shfl_xor(m, 32);
        if (lane < 16) xpack[pos] = (uint16_t)m;
    }
    grid.sync();

    // ---- Phase 1: layer 1, 32 branches/block (8 per wave). ----
    {
        const uint4* s = (const uint4*)xpack;
        uint4* d = (uint4*)lds;
#pragma unroll
        for (int k = 0; k < 8; ++k)
            d[k * 256 + tid] = s[k * 256 + tid];
    }
    __syncthreads();

    for (int k = 0; k < 8; ++k) {
        const int bidx = bk * 32 + wave * 8 + k;          // [0, NIN)
        const int* ip = idx1 + bidx * (NS * NSY) + lane;
        const uint32_t om = branch_mask(lds, ip);
        if (lane == 0) act1pack[bidx] = (uint16_t)om;
    }
    grid.sync();

    // ---- Phase 2: layer 2, t = 0 only. 4 branches/block (1 per wave). ----
    {
        const uint4* s = (const uint4*)act1pack;
        uint4* d = (uint4*)lds;
#pragma unroll
        for (int k = 0; k < 8; ++k)
            d[k * 256 + tid] = s[k * 256 + tid];
    }
    __syncthreads();

    {
        const int j  = bk * 4 + wave;                     // [0, 2048)
        const int c  = j >> 4;
        const int br = j & 15;
        // branch (c, t=0, br): offset = ((c*NT + 0)*NBR + br) * NS*NSY
        const int* ip = idx2 + (c * (NT * NBR) + br) * (NS * NSY) + lane;
        const uint32_t om = branch_mask(lds, ip);
        if (lane < NB) out[lane * (NC * NBR) + j] = (int)((om >> lane) & 1u);
    }
}

// ---------------------------------------------------------------------------
extern "C" void kernel_launch(void* const* d_in, const int* in_sizes, int n_in,
                              void* d_out, int out_size, void* d_ws, size_t ws_size,
                              hipStream_t stream) {
    const float* x    = (const float*)d_in[0];
    const int*   idx1 = (const int*)d_in[1];
    const int*   idx2 = (const int*)d_in[2];

    uint16_t* xpack    = (uint16_t*)d_ws;                       // 32 KB
    uint16_t* act1pack = (uint16_t*)((char*)d_ws + 32768);      // 32 KB
    int*      out      = (int*)d_out;

    void* args[] = {(void*)&x, (void*)&idx1, (void*)&idx2,
                    (void*)&xpack, (void*)&act1pack, (void*)&out};
    hipLaunchCooperativeKernel((const void*)k_fused, dim3(GRID), dim3(256),
                               args, 0, stream);
}